// Round 5
// baseline (65.701 us; speedup 1.0000x reference)
//
#include <hip/hip_runtime.h>
#include <hip/hip_cooperative_groups.h>
#include <math.h>

namespace cg = cooperative_groups;

#define STRIDE_F 8.0f
#define N_CLS 80
#define NA 3
#define NCH (5 + N_CLS)   // 85
#define NG 64
#define NGT 50
#define NANCH 9
#define EPS_T 1e-8f
#define MAIN_BLOCKS 24    // 24 blocks * 256 thr * 2 cells = NA*NG*NG

__device__ __forceinline__ float bce_logits(float x, float t) {
    return fmaxf(x, 0.0f) - x * t + log1pf(expf(-fabsf(x)));
}

// Single cooperative dispatch. grid = (MAIN_BLOCKS, nB).
// Phase A (bx==0 blocks only): per-GT prep -> gtws (4 float4 per GT):
//   q0 = corner box (xl,yt,xr,yb)
//   q1 = target ltrb logs
//   q2 = (0.375*areaG, key bits, wvec, cls)
//   q3 = (winner&&valid, 0, 0, 0)
// plus anyv[b], plus out[0]=0.
// grid.sync()
// Phase B (all blocks): stage GT tables to LDS, 2 cells/thread conf/bbox loss,
// class loss spread flat over threads, block reduce, one atomicAdd.
__global__ __launch_bounds__(256) void fcos_fused(
        const float* __restrict__ raw,
        const float* __restrict__ labels,
        const float* __restrict__ all_anchors,
        const int* __restrict__ anchor_indices,
        const int* __restrict__ img_size,
        float* __restrict__ gtws,
        int* __restrict__ anyv,
        float* __restrict__ out) {
    __shared__ int    sk[64];
    __shared__ float4 s_gt[NGT * 4];
    __shared__ float  swave[4];

    int b = blockIdx.y;
    int tid = threadIdx.x;

    // ---------------- phase A: per-batch GT prep (bx==0 blocks) -------------
    if (blockIdx.x == 0) {
        float fimg = (float)(*img_size);
        int valid = 0, key = -1, bn = 0;
        float gx = 0, gy = 0, gw = 0, gh = 0, cls = 0;
        if (tid < NGT) {
            const float* lab = labels + (b * NGT + tid) * 5;
            cls = lab[0];
            gx = lab[1]; gy = lab[2]; gw = lab[3]; gh = lab[4];
            int best = 0; float bi = -1.0f;
            for (int k = 0; k < NANCH; ++k) {
                float aw = all_anchors[2 * k], ah = all_anchors[2 * k + 1];
                float inter = fminf(gw, aw) * fminf(gh, ah);
                float iou = inter / (gw * gh + aw * ah - inter);
                if (iou > bi) { bi = iou; best = k; }
            }
            bn = best % NA;
            for (int j = 0; j < NA; ++j) if (anchor_indices[j] == best) valid = 1;
            int ti = (int)(gx / STRIDE_F);
            int tj = (int)(gy / STRIDE_F);
            key = valid ? ((bn << 12) | (tj << 6) | ti) : -1;
            sk[tid] = key;
        }
        __syncthreads();
        if (tid < NGT) {
            // JAX scatter "last valid update wins"
            int winner = valid;
            for (int gp = tid + 1; gp < NGT; ++gp)
                if (sk[gp] == key) winner = 0;

            int ai = anchor_indices[bn];
            float aw = all_anchors[2 * ai], ah = all_anchors[2 * ai + 1];
            float ccx = (floorf(gx / STRIDE_F) + 0.5f) * STRIDE_F;
            float ccy = (floorf(gy / STRIDE_F) + 0.5f) * STRIDE_F;
            float l   = fmaxf(ccx - (gx - gw * 0.5f), 0.0f);
            float t   = fmaxf(ccy - (gy - gh * 0.5f), 0.0f);
            float r   = fmaxf(gx + gw * 0.5f - ccx, 0.0f);
            float btm = fmaxf(gy + gh * 0.5f - ccy, 0.0f);

            float4* o = (float4*)(gtws + (b * NGT + tid) * 16);
            o[0] = make_float4(gx - gw * 0.5f, gy - gh * 0.5f,
                               gx + gw * 0.5f, gy + gh * 0.5f);
            o[1] = make_float4(logf(l / aw + EPS_T), logf(t / ah + EPS_T),
                               logf(r / aw + EPS_T), logf(btm / ah + EPS_T));
            o[2] = make_float4(0.375f * (gw * gh), __int_as_float(key),
                               2.0f - gw * gh / fimg / fimg, cls);
            o[3] = make_float4(winner ? 1.0f : 0.0f, 0.0f, 0.0f, 0.0f);
        }
        unsigned long long m = __ballot(valid != 0);
        if (tid == 0) {
            anyv[b] = (m != 0ULL) ? 1 : 0;
            if (b == 0) atomicExch(out, 0.0f);   // replaces the memset node
        }
    }

    cg::this_grid().sync();

    // ---------------- phase B: stage GT tables, main + cls ------------------
    const float4* w4 = (const float4*)(gtws + (size_t)b * NGT * 16);
    for (int i = tid; i < NGT * 4; i += 256) s_gt[i] = w4[i];
    __syncthreads();

    float fimg = (float)(*img_size);
    bool any_v = (anyv[b] != 0);

    int cp = (blockIdx.x * 256 + tid) * 2;   // flat cell id, even
    int a = cp >> 12;
    int y = (cp >> 6) & (NG - 1);
    int x0 = cp & (NG - 1);
    int ai = anchor_indices[a];
    float aw = all_anchors[2 * ai], ah = all_anchors[2 * ai + 1];

    const float* rb = raw + ((size_t)(b * (NA * NCH) + a * NCH) << 12)
                          + (y << 6) + x0;
    float2 r0 = *(const float2*)(rb);
    float2 r1 = *(const float2*)(rb + 1 * 4096);
    float2 r2 = *(const float2*)(rb + 2 * 4096);
    float2 r3 = *(const float2*)(rb + 3 * 4096);
    float2 r4 = *(const float2*)(rb + 4 * 4096);

    float pxl[2], pxr[2], pyt[2], pyb[2], basev[2];
    {
        float cy = ((float)y + 0.5f) * STRIDE_F;
        float lp, tp, rp, bp, px, py, pw, ph, cx;
        lp = fminf(expf(r0.x) * aw, fimg);
        tp = fminf(expf(r1.x) * ah, fimg);
        rp = fminf(expf(r2.x) * aw, fimg);
        bp = fminf(expf(r3.x) * ah, fimg);
        cx = ((float)x0 + 0.5f) * STRIDE_F;
        px = cx + (rp - lp) * 0.5f;
        py = cy + (bp - tp) * 0.5f;
        pw = lp + rp; ph = tp + bp;
        basev[0] = 0.375f * (pw * ph + 1e-12f);
        pxl[0] = px - pw * 0.5f; pxr[0] = px + pw * 0.5f;
        pyt[0] = py - ph * 0.5f; pyb[0] = py + ph * 0.5f;

        lp = fminf(expf(r0.y) * aw, fimg);
        tp = fminf(expf(r1.y) * ah, fimg);
        rp = fminf(expf(r2.y) * aw, fimg);
        bp = fminf(expf(r3.y) * ah, fimg);
        cx = ((float)x0 + 1.5f) * STRIDE_F;
        px = cx + (rp - lp) * 0.5f;
        py = cy + (bp - tp) * 0.5f;
        pw = lp + rp; ph = tp + bp;
        basev[1] = 0.375f * (pw * ph + 1e-12f);
        pxl[1] = px - pw * 0.5f; pxr[1] = px + pw * 0.5f;
        pyt[1] = py - ph * 0.5f; pyb[1] = py + ph * 0.5f;
    }

    // iou >= 0.6  <=>  inter >= 0.375*(areaP+1e-12) + 0.375*areaG
    // track m = max_g(inter - thr_g); compare vs base once at the end
    float maxd0 = -1e30f, maxd1 = -1e30f;
    int win0 = -1, win1 = -1;
    #pragma unroll 10
    for (int g = 0; g < NGT; ++g) {
        float4 bb = s_gt[g * 4 + 0];
        float4 q2 = s_gt[g * 4 + 2];
        {
            float tlx = fmaxf(pxl[0], bb.x);
            float tly = fmaxf(pyt[0], bb.y);
            float brx = fminf(pxr[0], bb.z);
            float bry = fminf(pyb[0], bb.w);
            float inter = fmaxf(brx - tlx, 0.0f) * fmaxf(bry - tly, 0.0f);
            maxd0 = fmaxf(maxd0, inter - q2.x);
        }
        {
            float tlx = fmaxf(pxl[1], bb.x);
            float tly = fmaxf(pyt[1], bb.y);
            float brx = fminf(pxr[1], bb.z);
            float bry = fminf(pyb[1], bb.w);
            float inter = fmaxf(brx - tlx, 0.0f) * fmaxf(bry - tly, 0.0f);
            maxd1 = fmaxf(maxd1, inter - q2.x);
        }
        int kk = __float_as_int(q2.y);
        if (kk == cp)     win0 = g;   // ascending g: last match wins
        if (kk == cp + 1) win1 = g;
    }

    float loss = 0.0f;
    if (win0 >= 0) {
        loss += bce_logits(r4.x, 1.0f);
        float4 tl = s_gt[win0 * 4 + 1];
        float w = s_gt[win0 * 4 + 2].z;
        float d0 = r0.x - tl.x, d1 = r1.x - tl.y, d2 = r2.x - tl.z, d3 = r3.x - tl.w;
        loss += 0.5f * w * (d0 * d0 + d1 * d1 + d2 * d2 + d3 * d3);
    } else if (!any_v || maxd0 < basev[0]) {
        loss += bce_logits(r4.x, 0.0f);
    }
    if (win1 >= 0) {
        loss += bce_logits(r4.y, 1.0f);
        float4 tl = s_gt[win1 * 4 + 1];
        float w = s_gt[win1 * 4 + 2].z;
        float d0 = r0.y - tl.x, d1 = r1.y - tl.y, d2 = r2.y - tl.z, d3 = r3.y - tl.w;
        loss += 0.5f * w * (d0 * d0 + d1 * d1 + d2 * d2 + d3 * d3);
    } else if (!any_v || maxd1 < basev[1]) {
        loss += bce_logits(r4.y, 0.0f);
    }

    // ---------------- class loss, spread flat over threads ------------------
    int tb = blockIdx.x * 256 + tid;         // [0, 6144)
    if (tb < NGT * N_CLS) {
        int g = tb / N_CLS;
        int cc = tb - g * N_CLS;
        float4 q2 = s_gt[g * 4 + 2];
        if (s_gt[g * 4 + 3].x != 0.0f) {
            int k = __float_as_int(q2.y);
            int bn2 = k >> 12;
            int tj = (k >> 6) & (NG - 1);
            int ti = k & (NG - 1);
            const float* rc = raw
                + ((size_t)(b * (NA * NCH) + bn2 * NCH + 5 + cc) << 12)
                + (tj << 6) + ti;
            loss += bce_logits(*rc, (cc == (int)q2.w) ? 1.0f : 0.0f);
        }
    }

    // ---------------- block reduction + one atomic --------------------------
    for (int off = 32; off > 0; off >>= 1)
        loss += __shfl_down(loss, off, 64);
    if ((tid & 63) == 0) swave[tid >> 6] = loss;
    __syncthreads();
    if (tid == 0)
        atomicAdd(out, swave[0] + swave[1] + swave[2] + swave[3]);
}

extern "C" void kernel_launch(void* const* d_in, const int* in_sizes, int n_in,
                              void* d_out, int out_size, void* d_ws, size_t ws_size,
                              hipStream_t stream) {
    const float* raw            = (const float*)d_in[0];
    const float* labels         = (const float*)d_in[1];
    const float* all_anchors    = (const float*)d_in[2];
    const int*   anchor_indices = (const int*)d_in[3];
    const int*   img_size       = (const int*)d_in[4];
    float* out = (float*)d_out;

    int nB = in_sizes[0] / (NA * NCH * NG * NG);   // 16

    float* gtws = (float*)d_ws;
    int*   anyv = (int*)((char*)d_ws + (size_t)nB * NGT * 16 * sizeof(float));

    void* kargs[] = {
        (void*)&raw, (void*)&labels, (void*)&all_anchors,
        (void*)&anchor_indices, (void*)&img_size,
        (void*)&gtws, (void*)&anyv, (void*)&out
    };
    hipLaunchCooperativeKernel(reinterpret_cast<void*>(fcos_fused),
                               dim3(MAIN_BLOCKS, nB), dim3(256, 1, 1),
                               kargs, 0, stream);
}

// Round 6
// 19.846 us; speedup vs baseline: 3.3105x; 3.3105x over previous
//
#include <hip/hip_runtime.h>
#include <math.h>

#define STRIDE_F 8.0f
#define N_CLS 80
#define NA 3
#define NCH (5 + N_CLS)   // 85
#define NG 64
#define NGT 50
#define NANCH 9
#define EPS_T 1e-8f
#define MAIN_BLOCKS 12    // 12 blocks * 256 thr * 4 cells = NA*NG*NG

__device__ __forceinline__ float bce_logits(float x, float t) {
    return fmaxf(x, 0.0f) - x * t + log1pf(expf(-fabsf(x)));
}

// grid = (MAIN_BLOCKS, nB). Each block redundantly computes per-GT prep into
// LDS (one wave), then each thread owns 4 adjacent x-cells (float4 loads).
// Class-loss pairs (<=50x80=4000) spread flat: thread tb takes pair tb and
// pair tb+3072 (tb<928). Block partial -> ws; tiny reduce kernel sums to out.
__global__ __launch_bounds__(256) void fcos_fused(
        const float* __restrict__ raw,
        const float* __restrict__ labels,
        const float* __restrict__ all_anchors,
        const int* __restrict__ anchor_indices,
        const int* __restrict__ img_size,
        float* __restrict__ partials) {
    __shared__ float4 s_box[NGT];   // corner box (xl,yt,xr,yb)
    __shared__ float4 s_tl[NGT];    // target ltrb logs
    __shared__ float2 s_tk[NGT];    // (0.375*areaG, key-as-float-bits)
    __shared__ int    s_key[NGT];
    __shared__ float  s_wv[NGT];
    __shared__ int    s_cls[NGT];
    __shared__ int    s_win[NGT];
    __shared__ int    s_any;
    __shared__ float  swave[4];

    int b = blockIdx.y;
    int tid = threadIdx.x;
    float fimg = (float)(*img_size);

    // ---------------- per-block GT prep (threads 0..49, wave 0) -------------
    int valid = 0, key = -1, bn = 0;
    float gx = 0, gy = 0, gw = 0, gh = 0, cls = 0;
    if (tid < NGT) {
        const float* lab = labels + (b * NGT + tid) * 5;
        cls = lab[0];
        gx = lab[1]; gy = lab[2]; gw = lab[3]; gh = lab[4];
        int best = 0; float bi = -1.0f;
        for (int k = 0; k < NANCH; ++k) {
            float aw = all_anchors[2 * k], ah = all_anchors[2 * k + 1];
            float inter = fminf(gw, aw) * fminf(gh, ah);
            float iou = inter / (gw * gh + aw * ah - inter);
            if (iou > bi) { bi = iou; best = k; }
        }
        bn = best % NA;
        for (int j = 0; j < NA; ++j) if (anchor_indices[j] == best) valid = 1;
        int ti = (int)(gx / STRIDE_F);
        int tj = (int)(gy / STRIDE_F);
        key = valid ? ((bn << 12) | (tj << 6) | ti) : -1;
        s_key[tid] = key;
    }
    __syncthreads();
    if (tid < NGT) {
        // JAX scatter "last valid update wins"
        int winner = valid;
        for (int gp = tid + 1; gp < NGT; ++gp)
            if (s_key[gp] == key) winner = 0;

        int ai = anchor_indices[bn];
        float aw = all_anchors[2 * ai], ah = all_anchors[2 * ai + 1];
        float ccx = (floorf(gx / STRIDE_F) + 0.5f) * STRIDE_F;
        float ccy = (floorf(gy / STRIDE_F) + 0.5f) * STRIDE_F;
        float l   = fmaxf(ccx - (gx - gw * 0.5f), 0.0f);
        float t   = fmaxf(ccy - (gy - gh * 0.5f), 0.0f);
        float r   = fmaxf(gx + gw * 0.5f - ccx, 0.0f);
        float btm = fmaxf(gy + gh * 0.5f - ccy, 0.0f);

        s_box[tid] = make_float4(gx - gw * 0.5f, gy - gh * 0.5f,
                                 gx + gw * 0.5f, gy + gh * 0.5f);
        s_tk[tid]  = make_float2(0.375f * (gw * gh), __int_as_float(key));
        s_tl[tid]  = make_float4(logf(l / aw + EPS_T), logf(t / ah + EPS_T),
                                 logf(r / aw + EPS_T), logf(btm / ah + EPS_T));
        s_wv[tid]  = 2.0f - gw * gh / fimg / fimg;
        s_cls[tid] = (int)cls;
        s_win[tid] = winner;
    }
    unsigned long long m = __ballot(valid != 0);   // wave 0 holds all GT lanes
    if (tid == 0) s_any = (m != 0ULL);
    __syncthreads();

    // ---------------- main: 4 cells per thread ------------------------------
    int cp = (blockIdx.x * 256 + tid) * 4;   // flat cell id, multiple of 4
    int a = cp >> 12;
    int y = (cp >> 6) & (NG - 1);
    int x0 = cp & (NG - 1);
    int ai = anchor_indices[a];
    float aw = all_anchors[2 * ai], ah = all_anchors[2 * ai + 1];

    const float* rb = raw + ((size_t)(b * (NA * NCH) + a * NCH) << 12)
                          + (y << 6) + x0;
    float4 r0 = *(const float4*)(rb);
    float4 r1 = *(const float4*)(rb + 1 * 4096);
    float4 r2 = *(const float4*)(rb + 2 * 4096);
    float4 r3 = *(const float4*)(rb + 3 * 4096);
    float4 r4 = *(const float4*)(rb + 4 * 4096);

    float pxl[4], pxr[4], pyt[4], pyb[4], basev[4];
    {
        const float* p0 = (const float*)&r0;
        const float* p1 = (const float*)&r1;
        const float* p2 = (const float*)&r2;
        const float* p3 = (const float*)&r3;
        float cy = ((float)y + 0.5f) * STRIDE_F;
        #pragma unroll 4
        for (int j = 0; j < 4; ++j) {
            float lp = fminf(expf(p0[j]) * aw, fimg);
            float tp = fminf(expf(p1[j]) * ah, fimg);
            float rp = fminf(expf(p2[j]) * aw, fimg);
            float bp = fminf(expf(p3[j]) * ah, fimg);
            float cx = ((float)(x0 + j) + 0.5f) * STRIDE_F;
            float px = cx + (rp - lp) * 0.5f;
            float py = cy + (bp - tp) * 0.5f;
            float pw = lp + rp, ph = tp + bp;
            basev[j] = 0.375f * (pw * ph + 1e-12f);
            pxl[j] = px - pw * 0.5f; pxr[j] = px + pw * 0.5f;
            pyt[j] = py - ph * 0.5f; pyb[j] = py + ph * 0.5f;
        }
    }

    // iou >= 0.6  <=>  inter >= 0.375*(areaP+1e-12) + 0.375*areaG
    float maxd[4] = {-1e30f, -1e30f, -1e30f, -1e30f};
    int win0 = -1, win1 = -1, win2 = -1, win3 = -1;
    #pragma unroll 5
    for (int g = 0; g < NGT; ++g) {
        float4 bb = s_box[g];
        float2 tk = s_tk[g];
        #pragma unroll 4
        for (int j = 0; j < 4; ++j) {
            float tlx = fmaxf(pxl[j], bb.x);
            float tly = fmaxf(pyt[j], bb.y);
            float brx = fminf(pxr[j], bb.z);
            float bry = fminf(pyb[j], bb.w);
            float inter = fmaxf(brx - tlx, 0.0f) * fmaxf(bry - tly, 0.0f);
            maxd[j] = fmaxf(maxd[j], inter - tk.x);
        }
        unsigned d = (unsigned)(__float_as_int(tk.y) - cp);
        if (d < 4u) {            // rare: this GT targets one of my 4 cells
            win0 = (d == 0u) ? g : win0;   // ascending g: last match wins
            win1 = (d == 1u) ? g : win1;
            win2 = (d == 2u) ? g : win2;
            win3 = (d == 3u) ? g : win3;
        }
    }

    float loss = 0.0f;
    bool any_v = (s_any != 0);
    const float* q4 = (const float*)&r4;
    const float* q0 = (const float*)&r0;
    const float* q1 = (const float*)&r1;
    const float* q2 = (const float*)&r2;
    const float* q3 = (const float*)&r3;
    int winv[4] = {win0, win1, win2, win3};
    #pragma unroll 4
    for (int j = 0; j < 4; ++j) {
        int w = winv[j];
        if (w >= 0) {
            loss += bce_logits(q4[j], 1.0f);
            float4 tl = s_tl[w];
            float wv = s_wv[w];
            float d0 = q0[j] - tl.x, d1 = q1[j] - tl.y;
            float d2 = q2[j] - tl.z, d3 = q3[j] - tl.w;
            loss += 0.5f * wv * (d0 * d0 + d1 * d1 + d2 * d2 + d3 * d3);
        } else if (!any_v || maxd[j] < basev[j]) {
            loss += bce_logits(q4[j], 0.0f);
        }
    }

    // ---------------- class loss, spread flat over threads ------------------
    int tb = blockIdx.x * 256 + tid;         // [0, 3072)
    {
        int g = tb / N_CLS;
        int cc = tb - g * N_CLS;
        if (s_win[g]) {
            int k = s_key[g];
            const float* rc = raw
                + ((size_t)(b * (NA * NCH) + (k >> 12) * NCH + 5 + cc) << 12)
                + (k & 0xFFF);
            loss += bce_logits(*rc, (cc == s_cls[g]) ? 1.0f : 0.0f);
        }
    }
    if (tb < NGT * N_CLS - 3072) {           // tb < 928: second pair
        int t2 = tb + 3072;
        int g = t2 / N_CLS;
        int cc = t2 - g * N_CLS;
        if (s_win[g]) {
            int k = s_key[g];
            const float* rc = raw
                + ((size_t)(b * (NA * NCH) + (k >> 12) * NCH + 5 + cc) << 12)
                + (k & 0xFFF);
            loss += bce_logits(*rc, (cc == s_cls[g]) ? 1.0f : 0.0f);
        }
    }

    // ---------------- block reduction -> partial ----------------------------
    for (int off = 32; off > 0; off >>= 1)
        loss += __shfl_down(loss, off, 64);
    if ((tid & 63) == 0) swave[tid >> 6] = loss;
    __syncthreads();
    if (tid == 0)
        partials[b * MAIN_BLOCKS + blockIdx.x] =
            swave[0] + swave[1] + swave[2] + swave[3];
}

// Sum the per-block partials (n <= 256) and store the scalar output.
__global__ __launch_bounds__(256) void fcos_reduce(
        const float* __restrict__ partials, float* __restrict__ out, int n) {
    int t = threadIdx.x;
    float v = (t < n) ? partials[t] : 0.0f;
    for (int off = 32; off > 0; off >>= 1)
        v += __shfl_down(v, off, 64);
    __shared__ float sw[4];
    if ((t & 63) == 0) sw[t >> 6] = v;
    __syncthreads();
    if (t == 0) out[0] = sw[0] + sw[1] + sw[2] + sw[3];
}

extern "C" void kernel_launch(void* const* d_in, const int* in_sizes, int n_in,
                              void* d_out, int out_size, void* d_ws, size_t ws_size,
                              hipStream_t stream) {
    const float* raw            = (const float*)d_in[0];
    const float* labels         = (const float*)d_in[1];
    const float* all_anchors    = (const float*)d_in[2];
    const int*   anchor_indices = (const int*)d_in[3];
    const int*   img_size       = (const int*)d_in[4];
    float* out = (float*)d_out;

    int nB = in_sizes[0] / (NA * NCH * NG * NG);   // 16
    float* partials = (float*)d_ws;
    int nPart = nB * MAIN_BLOCKS;                  // 192

    fcos_fused<<<dim3(MAIN_BLOCKS, nB), 256, 0, stream>>>(
        raw, labels, all_anchors, anchor_indices, img_size, partials);
    fcos_reduce<<<1, 256, 0, stream>>>(partials, out, nPart);
}